// Round 1
// baseline (388.383 us; speedup 1.0000x reference)
//
#include <hip/hip_runtime.h>
#include <hip/hip_bf16.h>

#define H_DIM 768
#define E_DIM 128
#define NQ 64
#define LQ 32
#define ND 256
#define LD 180
#define QTOK (NQ*LQ)          // 2048
#define DTOK (ND*LD)          // 46080
#define TTOK (QTOK+DTOK)      // 48128

typedef __attribute__((ext_vector_type(8))) short short8;
typedef __attribute__((ext_vector_type(4))) float f32x4;
typedef __attribute__((ext_vector_type(4))) float float4v;
typedef __attribute__((ext_vector_type(4))) unsigned short ushort4v;

__device__ __forceinline__ unsigned short f2bf(float f) {
    union { float f; unsigned u; } v;
    v.f = f;
    unsigned r = v.u + 0x7fffu + ((v.u >> 16) & 1u);
    return (unsigned short)(r >> 16);
}

// ---------------------------------------------------------------------------
// prep: W1T[col][k] = bf16(W1[k][col]), W2T[col][k] = bf16(W2[k][col]),
//       qcnt[q] = sum(query_mask[q,:])
// ---------------------------------------------------------------------------
__global__ __launch_bounds__(256) void prep_kernel(
    const float* __restrict__ W1, const float* __restrict__ W2,
    const int* __restrict__ qmask,
    unsigned short* __restrict__ W1T, unsigned short* __restrict__ W2T,
    float* __restrict__ qcnt)
{
    int tid = blockIdx.x * 256 + threadIdx.x;
    int nth = gridDim.x * 256;
    for (int idx = tid; idx < H_DIM * H_DIM; idx += nth) {
        int k = idx / H_DIM, c = idx - k * H_DIM;
        W1T[(size_t)c * H_DIM + k] = f2bf(W1[idx]);
    }
    for (int idx = tid; idx < H_DIM * E_DIM; idx += nth) {
        int k = idx / E_DIM, c = idx - k * E_DIM;
        W2T[(size_t)c * H_DIM + k] = f2bf(W2[idx]);
    }
    if (tid < NQ) {
        int s = 0;
        for (int i = 0; i < LQ; ++i) s += qmask[tid * LQ + i];
        qcnt[tid] = (float)s;
    }
}

// ---------------------------------------------------------------------------
// head: per 128-token tile, fused  E = relu(X@W1+b1)@W2 + b2, mask, l2norm
// 512 threads = 8 waves arranged 4(M)x2(N) over a 128x128 tile.
// LDS: T1[128][128] bf16 (32KB) | union{ XP[128][64]+W1P[128][64] , W2P[128][128] } (32KB)
// all tiles XOR-swizzled: byte ^= (row&7)<<4
// ---------------------------------------------------------------------------
__global__ __launch_bounds__(512) void head_kernel(
    const float* __restrict__ qh, const float* __restrict__ dh,
    const int* __restrict__ qmv, const int* __restrict__ dmv,
    const float* __restrict__ b1, const float* __restrict__ b2,
    const unsigned short* __restrict__ W1T, const unsigned short* __restrict__ W2T,
    unsigned short* __restrict__ emb)
{
    __shared__ char lds_raw[65536];
    char* T1  = lds_raw;            // 32KB
    char* XP  = lds_raw + 32768;    // 16KB (phase A)
    char* W1P = lds_raw + 49152;    // 16KB (phase A)
    char* W2P = lds_raw + 32768;    // 32KB (phase B, aliases XP/W1P)

    const int tid  = threadIdx.x;
    const int lane = tid & 63;
    const int wv   = tid >> 6;      // 0..7
    const int wm   = wv >> 1;       // 0..3 : rows [wm*32, +32)
    const int wn   = wv & 1;        // 0..1 : cols [wn*64, +64)
    const int t0   = blockIdx.x * 128;
    const int l15  = lane & 15;
    const int lhi  = lane >> 4;

    const f32x4 zero4 = {0.0f, 0.0f, 0.0f, 0.0f};

    f32x4 eacc[2][4];
    #pragma unroll
    for (int mt = 0; mt < 2; ++mt)
        #pragma unroll
        for (int nt = 0; nt < 4; ++nt)
            eacc[mt][nt] = zero4;

    const int srow = tid >> 2;      // 0..127
    const int sgrp = tid & 3;
    const float* xsrc_base = (t0 + srow < QTOK)
        ? (qh + (size_t)(t0 + srow) * H_DIM)
        : (dh + (size_t)(t0 + srow - QTOK) * H_DIM);

    for (int jb = 0; jb < 6; ++jb) {
        f32x4 pacc[2][4];
        #pragma unroll
        for (int mt = 0; mt < 2; ++mt)
            #pragma unroll
            for (int nt = 0; nt < 4; ++nt)
                pacc[mt][nt] = zero4;

        for (int kb = 0; kb < 12; ++kb) {
            __syncthreads();
            // stage XP: [128 rows][64 k] from f32, convert to bf16
            {
                const float* src = xsrc_base + kb * 64 + sgrp * 16;
                #pragma unroll
                for (int i = 0; i < 4; ++i) {
                    float4v v = *(const float4v*)(src + i * 4);
                    ushort4v u;
                    u.x = f2bf(v.x); u.y = f2bf(v.y); u.z = f2bf(v.z); u.w = f2bf(v.w);
                    int byte = srow * 128 + (sgrp * 16 + i * 4) * 2;
                    byte ^= (srow & 7) << 4;
                    *(ushort4v*)(XP + byte) = u;
                }
            }
            // stage W1P: [128 cols][64 k] from pre-transposed W1T (bf16)
            {
                const unsigned short* src = W1T + (size_t)(jb * 128 + srow) * H_DIM + kb * 64;
                #pragma unroll
                for (int i = 0; i < 2; ++i) {
                    int k8 = sgrp * 16 + i * 8;
                    short8 v = *(const short8*)(src + k8);
                    int byte = srow * 128 + k8 * 2;
                    byte ^= (srow & 7) << 4;
                    *(short8*)(W1P + byte) = v;
                }
            }
            __syncthreads();
            #pragma unroll
            for (int ks = 0; ks < 2; ++ks) {
                short8 af[2], bfr[4];
                #pragma unroll
                for (int mt = 0; mt < 2; ++mt) {
                    int row = wm * 32 + mt * 16 + l15;
                    int byte = row * 128 + (ks * 32 + lhi * 8) * 2;
                    byte ^= (row & 7) << 4;
                    af[mt] = *(const short8*)(XP + byte);
                }
                #pragma unroll
                for (int nt = 0; nt < 4; ++nt) {
                    int col = wn * 64 + nt * 16 + l15;
                    int byte = col * 128 + (ks * 32 + lhi * 8) * 2;
                    byte ^= (col & 7) << 4;
                    bfr[nt] = *(const short8*)(W1P + byte);
                }
                #pragma unroll
                for (int mt = 0; mt < 2; ++mt)
                    #pragma unroll
                    for (int nt = 0; nt < 4; ++nt)
                        pacc[mt][nt] = __builtin_amdgcn_mfma_f32_16x16x32_bf16(
                            af[mt], bfr[nt], pacc[mt][nt], 0, 0, 0);
            }
        }

        // phase A epilogue: bias + relu -> T1 (bf16, swizzled)
        #pragma unroll
        for (int nt = 0; nt < 4; ++nt) {
            int col = wn * 64 + nt * 16 + l15;
            float bb = b1[jb * 128 + col];
            #pragma unroll
            for (int mt = 0; mt < 2; ++mt) {
                #pragma unroll
                for (int r = 0; r < 4; ++r) {
                    int row = wm * 32 + mt * 16 + lhi * 4 + r;
                    float v = pacc[mt][nt][r] + bb;
                    v = v > 0.0f ? v : 0.0f;
                    int byte = row * 256 + col * 2;
                    byte ^= (row & 7) << 4;
                    *(unsigned short*)(T1 + byte) = f2bf(v);
                }
            }
        }
        __syncthreads();
        // stage W2P: [128 cols][128 k] from pre-transposed W2T
        {
            const unsigned short* src = W2T + (size_t)srow * H_DIM + jb * 128;
            #pragma unroll
            for (int i = 0; i < 4; ++i) {
                int k8 = sgrp * 32 + i * 8;
                short8 v = *(const short8*)(src + k8);
                int byte = srow * 256 + k8 * 2;
                byte ^= (srow & 7) << 4;
                *(short8*)(W2P + byte) = v;
            }
        }
        __syncthreads();
        // phase B: E += T1 @ W2panel
        #pragma unroll
        for (int ks = 0; ks < 4; ++ks) {
            short8 af[2], bfr[4];
            #pragma unroll
            for (int mt = 0; mt < 2; ++mt) {
                int row = wm * 32 + mt * 16 + l15;
                int byte = row * 256 + (ks * 32 + lhi * 8) * 2;
                byte ^= (row & 7) << 4;
                af[mt] = *(const short8*)(T1 + byte);
            }
            #pragma unroll
            for (int nt = 0; nt < 4; ++nt) {
                int col = wn * 64 + nt * 16 + l15;
                int byte = col * 256 + (ks * 32 + lhi * 8) * 2;
                byte ^= (col & 7) << 4;
                bfr[nt] = *(const short8*)(W2P + byte);
            }
            #pragma unroll
            for (int mt = 0; mt < 2; ++mt)
                #pragma unroll
                for (int nt = 0; nt < 4; ++nt)
                    eacc[mt][nt] = __builtin_amdgcn_mfma_f32_16x16x32_bf16(
                        af[mt], bfr[nt], eacc[mt][nt], 0, 0, 0);
        }
    }

    // final epilogue: +b2, mask, L2-normalize per token row, store bf16
    __syncthreads();
    float* rs = (float*)lds_raw;    // [8][32] row sum-of-squares
    float b2v[4];
    #pragma unroll
    for (int nt = 0; nt < 4; ++nt) b2v[nt] = b2[wn * 64 + nt * 16 + l15];

    float vals[2][4][4];
    float sq[2][4];
    #pragma unroll
    for (int mt = 0; mt < 2; ++mt) {
        #pragma unroll
        for (int r = 0; r < 4; ++r) {
            int row = wm * 32 + mt * 16 + lhi * 4 + r;
            int t = t0 + row;
            int m = (t < QTOK) ? qmv[t] : dmv[t - QTOK];
            float fm = (float)m;
            float s = 0.0f;
            #pragma unroll
            for (int nt = 0; nt < 4; ++nt) {
                float v = (eacc[mt][nt][r] + b2v[nt]) * fm;
                vals[mt][nt][r] = v;
                s += v * v;
            }
            sq[mt][r] = s;
        }
    }
    #pragma unroll
    for (int m1 = 1; m1 < 16; m1 <<= 1) {
        #pragma unroll
        for (int mt = 0; mt < 2; ++mt)
            #pragma unroll
            for (int r = 0; r < 4; ++r)
                sq[mt][r] += __shfl_xor(sq[mt][r], m1, 64);
    }
    if (l15 == 0) {
        #pragma unroll
        for (int mt = 0; mt < 2; ++mt)
            #pragma unroll
            for (int r = 0; r < 4; ++r)
                rs[wv * 32 + mt * 16 + lhi * 4 + r] = sq[mt][r];
    }
    __syncthreads();
    #pragma unroll
    for (int mt = 0; mt < 2; ++mt) {
        #pragma unroll
        for (int r = 0; r < 4; ++r) {
            int row_in = mt * 16 + lhi * 4 + r;
            float tot = rs[(wm * 2) * 32 + row_in] + rs[(wm * 2 + 1) * 32 + row_in];
            float scale = 1.0f / fmaxf(sqrtf(tot), 1e-12f);
            int t = t0 + wm * 32 + row_in;
            #pragma unroll
            for (int nt = 0; nt < 4; ++nt)
                emb[(size_t)t * E_DIM + wn * 64 + nt * 16 + l15] =
                    f2bf(vals[mt][nt][r] * scale);
        }
    }
}

// ---------------------------------------------------------------------------
// score: one block per (q,d). S[32,192] = qe[32,128] @ de[192,128]^T via MFMA,
// masked max over doc tokens, sum over query tokens, / qcnt.
// Fragments load straight from global (row-major [tok,128] bf16 = 8 contig k).
// ---------------------------------------------------------------------------
__global__ __launch_bounds__(256) void score_kernel(
    const unsigned short* __restrict__ emb, const int* __restrict__ dmask,
    const float* __restrict__ qcnt, float* __restrict__ out)
{
    __shared__ float red[4][32];
    const int blk = blockIdx.x;
    const int q = blk >> 8;
    const int d = blk & 255;
    const int lane = threadIdx.x & 63;
    const int wv = threadIdx.x >> 6;   // 0..3, cols [wv*48, +48)
    const int l15 = lane & 15;
    const int lhi = lane >> 4;

    const unsigned short* qe = emb + (size_t)q * LQ * E_DIM;
    const unsigned short* de = emb + (size_t)(QTOK + d * LD) * E_DIM;

    const f32x4 zero4 = {0.0f, 0.0f, 0.0f, 0.0f};

    short8 af[2][4];
    #pragma unroll
    for (int mt = 0; mt < 2; ++mt)
        #pragma unroll
        for (int ks = 0; ks < 4; ++ks)
            af[mt][ks] = *(const short8*)(qe + (size_t)(mt * 16 + l15) * E_DIM + ks * 32 + lhi * 8);

    float rmax[2][4];
    #pragma unroll
    for (int mt = 0; mt < 2; ++mt)
        #pragma unroll
        for (int r = 0; r < 4; ++r)
            rmax[mt][r] = -3.0e38f;

    #pragma unroll
    for (int ntl = 0; ntl < 3; ++ntl) {
        int j = wv * 48 + ntl * 16 + l15;
        int jv = (j < LD) ? j : 0;
        const unsigned short* dr = de + (size_t)jv * E_DIM;
        short8 bfr[4];
        #pragma unroll
        for (int ks = 0; ks < 4; ++ks)
            bfr[ks] = *(const short8*)(dr + ks * 32 + lhi * 8);
        f32x4 acc[2];
        acc[0] = zero4; acc[1] = zero4;
        #pragma unroll
        for (int ks = 0; ks < 4; ++ks) {
            acc[0] = __builtin_amdgcn_mfma_f32_16x16x32_bf16(af[0][ks], bfr[ks], acc[0], 0, 0, 0);
            acc[1] = __builtin_amdgcn_mfma_f32_16x16x32_bf16(af[1][ks], bfr[ks], acc[1], 0, 0, 0);
        }
        float mval = (j < LD) ? (float)dmask[d * LD + j] : -1.0f;
        #pragma unroll
        for (int mt = 0; mt < 2; ++mt)
            #pragma unroll
            for (int r = 0; r < 4; ++r) {
                float v = (mval < 0.0f) ? -3.0e38f : acc[mt][r] * mval;
                rmax[mt][r] = fmaxf(rmax[mt][r], v);
            }
    }
    // max across the 16 columns within each tile (lanes share rows for m<16)
    #pragma unroll
    for (int m1 = 1; m1 < 16; m1 <<= 1)
        #pragma unroll
        for (int mt = 0; mt < 2; ++mt)
            #pragma unroll
            for (int r = 0; r < 4; ++r)
                rmax[mt][r] = fmaxf(rmax[mt][r], __shfl_xor(rmax[mt][r], m1, 64));

    if (l15 == 0) {
        #pragma unroll
        for (int mt = 0; mt < 2; ++mt)
            #pragma unroll
            for (int r = 0; r < 4; ++r)
                red[wv][mt * 16 + lhi * 4 + r] = rmax[mt][r];
    }
    __syncthreads();
    if (threadIdx.x < 64) {
        float v = 0.0f;
        if (lane < 32) {
            float m = red[0][lane];
            m = fmaxf(m, red[1][lane]);
            m = fmaxf(m, red[2][lane]);
            m = fmaxf(m, red[3][lane]);
            v = m;
        }
        #pragma unroll
        for (int off = 32; off > 0; off >>= 1)
            v += __shfl_xor(v, off, 64);
        if (lane == 0) out[q * ND + d] = v / qcnt[q];
    }
}

extern "C" void kernel_launch(void* const* d_in, const int* in_sizes, int n_in,
                              void* d_out, int out_size, void* d_ws, size_t ws_size,
                              hipStream_t stream)
{
    const float* qh = (const float*)d_in[0];
    const float* dh = (const float*)d_in[1];
    const int*   qm = (const int*)d_in[2];
    const int*   dm = (const int*)d_in[3];
    const float* W1 = (const float*)d_in[4];
    const float* b1 = (const float*)d_in[5];
    const float* W2 = (const float*)d_in[6];
    const float* b2 = (const float*)d_in[7];
    float* out = (float*)d_out;

    unsigned short* emb = (unsigned short*)d_ws;                  // [48128][128] bf16
    unsigned short* W1T = emb + (size_t)TTOK * E_DIM;             // [768][768]  bf16
    unsigned short* W2T = W1T + (size_t)H_DIM * H_DIM;            // [128][768]  bf16
    float* qcnt = (float*)(W2T + (size_t)E_DIM * H_DIM);          // [64] f32

    prep_kernel<<<256, 256, 0, stream>>>(W1, W2, qm, W1T, W2T, qcnt);
    head_kernel<<<TTOK / 128, 512, 0, stream>>>(qh, dh, qm, dm, b1, b2, W1T, W2T, emb);
    score_kernel<<<NQ * ND, 256, 0, stream>>>(emb, dm, qcnt, out);
}

// Round 2
// 243.609 us; speedup vs baseline: 1.5943x; 1.5943x over previous
//
#include <hip/hip_runtime.h>
#include <hip/hip_bf16.h>

#define H_DIM 768
#define E_DIM 128
#define NQ 64
#define LQ 32
#define ND 256
#define LD 180
#define QTOK (NQ*LQ)          // 2048
#define DTOK (ND*LD)          // 46080
#define TTOK (QTOK+DTOK)      // 48128

typedef __attribute__((ext_vector_type(8))) short short8;
typedef __attribute__((ext_vector_type(4))) float f32x4;
typedef __attribute__((ext_vector_type(4))) float float4v;

__device__ __forceinline__ unsigned short f2bf(float f) {
    union { float f; unsigned u; } v;
    v.f = f;
    unsigned r = v.u + 0x7fffu + ((v.u >> 16) & 1u);
    return (unsigned short)(r >> 16);
}

// async global->LDS, 16B per lane. LDS dest is wave-uniform base + lane*16.
__device__ __forceinline__ void gl_lds16(const void* g, void* l) {
    __builtin_amdgcn_global_load_lds(
        (const __attribute__((address_space(1))) unsigned char*)g,
        (__attribute__((address_space(3))) unsigned char*)l, 16, 0, 0);
}

// ---------------------------------------------------------------------------
// prep: W1T[col][k]=bf16(W1[k][col]), W2T[col][k]=bf16(W2[k][col]), qcnt
// ---------------------------------------------------------------------------
__global__ __launch_bounds__(256) void prep_kernel(
    const float* __restrict__ W1, const float* __restrict__ W2,
    const int* __restrict__ qmask,
    unsigned short* __restrict__ W1T, unsigned short* __restrict__ W2T,
    float* __restrict__ qcnt)
{
    int tid = blockIdx.x * 256 + threadIdx.x;
    int nth = gridDim.x * 256;
    for (int idx = tid; idx < H_DIM * H_DIM; idx += nth) {
        int k = idx / H_DIM, c = idx - k * H_DIM;
        W1T[(size_t)c * H_DIM + k] = f2bf(W1[idx]);
    }
    for (int idx = tid; idx < H_DIM * E_DIM; idx += nth) {
        int k = idx / E_DIM, c = idx - k * E_DIM;
        W2T[(size_t)c * H_DIM + k] = f2bf(W2[idx]);
    }
    if (tid < NQ) {
        int s = 0;
        for (int i = 0; i < LQ; ++i) s += qmask[tid * LQ + i];
        qcnt[tid] = (float)s;
    }
}

// ---------------------------------------------------------------------------
// head: BM=64 tokens/block, fused  emb = l2norm(mask*(relu(X@W1+b1)@W2+b2))
// 256 thr = 4 waves (2M x 2N), wave tile 32 rows x 64 cols.
// LDS 40KB: Abuf 8K (jb0 only) | Bbuf 16K (W1 panel / W2 half) | T1 16K
// Bbuf staged by global_load_lds with pre-swizzled per-lane SOURCE (linear dest).
// jb0 converts X->bf16, stores row-major copy to xbf; jb>=1 loads A-frags
// straight from global (L3-resident).
// ---------------------------------------------------------------------------
__global__ __launch_bounds__(256, 3) void head_kernel(
    const float* __restrict__ qh, const float* __restrict__ dh,
    const int* __restrict__ qmv, const int* __restrict__ dmv,
    const float* __restrict__ b1, const float* __restrict__ b2,
    const unsigned short* __restrict__ W1T, const unsigned short* __restrict__ W2T,
    unsigned short* __restrict__ emb, unsigned short* __restrict__ xbf)
{
    __shared__ char lds[40960];
    char* Abuf = lds;            // 8KB  [64 rows][64 k] bf16, swz
    char* Bbuf = lds + 8192;     // 16KB [128 cols][64 k] bf16, swz
    char* T1   = lds + 24576;    // 16KB [64 rows][128 cols] bf16, swz

    const int tid = threadIdx.x;
    const int lane = tid & 63;
    const int wv = tid >> 6;          // 0..3
    const int wm = wv >> 1, wn = wv & 1;
    const int l15 = lane & 15, lhi = lane >> 4;
    const int t0 = blockIdx.x * 64;

    const float* xsrc = (t0 < QTOK) ? (qh + (size_t)t0 * H_DIM)
                                    : (dh + (size_t)(t0 - QTOK) * H_DIM);
    const int srow = tid >> 2;        // 0..63
    const int sseg = tid & 3;         // 0..3 (16 elems)

    // pre-swizzled source coords for Bbuf staging (dest o = i*4096 + wv*1024 + lane*16)
    int bcol[4], bk[4];
    #pragma unroll
    for (int i = 0; i < 4; ++i) {
        int o = i * 4096 + wv * 1024 + lane * 16;
        int col = o >> 7;
        int kk = ((o & 127) ^ ((col & 7) << 4)) >> 1;
        bcol[i] = col; bk[i] = kk;
    }

    const f32x4 zero4 = {0.f, 0.f, 0.f, 0.f};
    f32x4 eacc[2][4];
    #pragma unroll
    for (int mt = 0; mt < 2; ++mt)
        #pragma unroll
        for (int nt = 0; nt < 4; ++nt) eacc[mt][nt] = zero4;

    for (int jb = 0; jb < 6; ++jb) {
        f32x4 pacc[2][4];
        #pragma unroll
        for (int mt = 0; mt < 2; ++mt)
            #pragma unroll
            for (int nt = 0; nt < 4; ++nt) pacc[mt][nt] = zero4;

        for (int kb = 0; kb < 12; ++kb) {
            __syncthreads();                       // Bbuf/Abuf free
            #pragma unroll
            for (int i = 0; i < 4; ++i)
                gl_lds16(W1T + (size_t)(jb * 128 + bcol[i]) * H_DIM + kb * 64 + bk[i],
                         Bbuf + i * 4096 + wv * 1024);

            short8 afx[2][2];
            if (jb == 0) {
                const float* s = xsrc + (size_t)srow * H_DIM + kb * 64 + sseg * 16;
                union { unsigned short u[16]; short8 s8[2]; } t16;
                #pragma unroll
                for (int i = 0; i < 4; ++i) {
                    float4v v = *(const float4v*)(s + i * 4);
                    t16.u[i*4+0] = f2bf(v.x); t16.u[i*4+1] = f2bf(v.y);
                    t16.u[i*4+2] = f2bf(v.z); t16.u[i*4+3] = f2bf(v.w);
                }
                int base = srow * 128 + sseg * 32;
                int sw = (srow & 7) << 4;
                *(short8*)(Abuf + (base ^ sw)) = t16.s8[0];
                *(short8*)(Abuf + ((base + 16) ^ sw)) = t16.s8[1];
                if (xbf) {
                    unsigned short* xd = xbf + (size_t)(t0 + srow) * H_DIM + kb * 64 + sseg * 16;
                    *(short8*)(xd) = t16.s8[0];
                    *(short8*)(xd + 8) = t16.s8[1];
                }
            } else if (xbf) {
                #pragma unroll
                for (int mt = 0; mt < 2; ++mt)
                    #pragma unroll
                    for (int ks = 0; ks < 2; ++ks)
                        afx[mt][ks] = *(const short8*)(xbf +
                            (size_t)(t0 + wm*32 + mt*16 + l15) * H_DIM + kb*64 + ks*32 + lhi*8);
            } else {
                #pragma unroll
                for (int mt = 0; mt < 2; ++mt)
                    #pragma unroll
                    for (int ks = 0; ks < 2; ++ks) {
                        const float* p = xsrc + (size_t)(wm*32 + mt*16 + l15) * H_DIM + kb*64 + ks*32 + lhi*8;
                        float4v a = ((const float4v*)p)[0], b = ((const float4v*)p)[1];
                        union { unsigned short u[8]; short8 s8; } tt;
                        tt.u[0]=f2bf(a.x); tt.u[1]=f2bf(a.y); tt.u[2]=f2bf(a.z); tt.u[3]=f2bf(a.w);
                        tt.u[4]=f2bf(b.x); tt.u[5]=f2bf(b.y); tt.u[6]=f2bf(b.z); tt.u[7]=f2bf(b.w);
                        afx[mt][ks] = tt.s8;
                    }
            }
            __syncthreads();                       // staging complete
            if (jb == 0) {
                #pragma unroll
                for (int mt = 0; mt < 2; ++mt)
                    #pragma unroll
                    for (int ks = 0; ks < 2; ++ks) {
                        int row = wm*32 + mt*16 + l15;
                        int byte = (row * 128 + (ks*32 + lhi*8) * 2) ^ ((row & 7) << 4);
                        afx[mt][ks] = *(const short8*)(Abuf + byte);
                    }
            }
            #pragma unroll
            for (int ks = 0; ks < 2; ++ks) {
                short8 bfr[4];
                #pragma unroll
                for (int nt = 0; nt < 4; ++nt) {
                    int col = wn*64 + nt*16 + l15;
                    int byte = (col * 128 + (ks*32 + lhi*8) * 2) ^ ((col & 7) << 4);
                    bfr[nt] = *(const short8*)(Bbuf + byte);
                }
                // swapped: C[w1col][token] = T1^T  -> lane holds 4 consecutive w1cols
                #pragma unroll
                for (int nt = 0; nt < 4; ++nt)
                    #pragma unroll
                    for (int mt = 0; mt < 2; ++mt)
                        pacc[mt][nt] = __builtin_amdgcn_mfma_f32_16x16x32_bf16(
                            bfr[nt], afx[mt][ks], pacc[mt][nt], 0, 0, 0);
            }
        }

        // T1 write: bias+relu, 4 consecutive cols packed per b64 write
        #pragma unroll
        for (int mt = 0; mt < 2; ++mt) {
            int token = wm*32 + mt*16 + l15;
            int sw = (token & 7) << 4;
            #pragma unroll
            for (int nt = 0; nt < 4; ++nt) {
                int c0 = wn*64 + nt*16 + lhi*4;
                union { unsigned short u[4]; unsigned long long q; } pk;
                #pragma unroll
                for (int r = 0; r < 4; ++r) {
                    float v = pacc[mt][nt][r] + b1[jb*128 + c0 + r];
                    v = v > 0.f ? v : 0.f;
                    pk.u[r] = f2bf(v);
                }
                int byte = (token * 256 + c0 * 2) ^ sw;
                *(unsigned long long*)(T1 + byte) = pk.q;
            }
        }

        // phase B: eacc += T1 @ W2[jb-panel], two 64-k halves through Bbuf
        #pragma unroll
        for (int h = 0; h < 2; ++h) {
            __syncthreads();                       // T1 visible / Bbuf free
            #pragma unroll
            for (int i = 0; i < 4; ++i)
                gl_lds16(W2T + (size_t)bcol[i] * H_DIM + jb * 128 + h * 64 + bk[i],
                         Bbuf + i * 4096 + wv * 1024);
            __syncthreads();
            #pragma unroll
            for (int ks = 0; ks < 2; ++ks) {
                short8 at[2], bw[4];
                #pragma unroll
                for (int mt = 0; mt < 2; ++mt) {
                    int row = wm*32 + mt*16 + l15;
                    int byte = (row * 256 + (h*64 + ks*32 + lhi*8) * 2) ^ ((row & 7) << 4);
                    at[mt] = *(const short8*)(T1 + byte);
                }
                #pragma unroll
                for (int nt = 0; nt < 4; ++nt) {
                    int col = wn*64 + nt*16 + l15;
                    int byte = (col * 128 + (ks*32 + lhi*8) * 2) ^ ((col & 7) << 4);
                    bw[nt] = *(const short8*)(Bbuf + byte);
                }
                #pragma unroll
                for (int mt = 0; mt < 2; ++mt)
                    #pragma unroll
                    for (int nt = 0; nt < 4; ++nt)
                        eacc[mt][nt] = __builtin_amdgcn_mfma_f32_16x16x32_bf16(
                            at[mt], bw[nt], eacc[mt][nt], 0, 0, 0);
            }
        }
    }

    // epilogue: +b2, mask, L2-normalize, store bf16
    float* rs = (float*)lds;   // [4][32]
    float b2v[4];
    #pragma unroll
    for (int nt = 0; nt < 4; ++nt) b2v[nt] = b2[wn*64 + nt*16 + l15];

    float vals[2][4][4], sq[2][4];
    #pragma unroll
    for (int mt = 0; mt < 2; ++mt)
        #pragma unroll
        for (int r = 0; r < 4; ++r) {
            int ri = mt*16 + lhi*4 + r;
            int t = t0 + wm*32 + ri;
            float fm = (float)((t < QTOK) ? qmv[t] : dmv[t - QTOK]);
            float s = 0.f;
            #pragma unroll
            for (int nt = 0; nt < 4; ++nt) {
                float v = (eacc[mt][nt][r] + b2v[nt]) * fm;
                vals[mt][nt][r] = v;
                s += v * v;
            }
            sq[mt][r] = s;
        }
    #pragma unroll
    for (int m1 = 1; m1 < 16; m1 <<= 1)
        #pragma unroll
        for (int mt = 0; mt < 2; ++mt)
            #pragma unroll
            for (int r = 0; r < 4; ++r)
                sq[mt][r] += __shfl_xor(sq[mt][r], m1, 64);
    __syncthreads();
    if (l15 == 0) {
        #pragma unroll
        for (int mt = 0; mt < 2; ++mt)
            #pragma unroll
            for (int r = 0; r < 4; ++r)
                rs[wv*32 + mt*16 + lhi*4 + r] = sq[mt][r];
    }
    __syncthreads();
    #pragma unroll
    for (int mt = 0; mt < 2; ++mt)
        #pragma unroll
        for (int r = 0; r < 4; ++r) {
            int ri = mt*16 + lhi*4 + r;
            float tot = rs[(wm*2)*32 + ri] + rs[(wm*2+1)*32 + ri];
            float sc = 1.f / fmaxf(sqrtf(tot), 1e-12f);
            int t = t0 + wm*32 + ri;
            #pragma unroll
            for (int nt = 0; nt < 4; ++nt)
                emb[(size_t)t * E_DIM + wn*64 + nt*16 + l15] = f2bf(vals[mt][nt][r] * sc);
        }
}

// ---------------------------------------------------------------------------
// score: block = (8-q group, d). qe fragments persistent in regs; de staged
// once per block in LDS (3 chunks of 64 doc tokens). Masked max over doc
// tokens, sum over query tokens, /qcnt.
// ---------------------------------------------------------------------------
__global__ __launch_bounds__(256, 3) void score_kernel(
    const unsigned short* __restrict__ emb, const int* __restrict__ dmask,
    const float* __restrict__ qcnt, float* __restrict__ out)
{
    __shared__ char slds[16384 + 64];
    char* De = slds;                       // [64 tok][128 e] bf16 swz
    float* red = (float*)(slds + 16384);   // [8]

    const int d = blockIdx.x & 255;
    const int qg = blockIdx.x >> 8;
    const int tid = threadIdx.x, lane = tid & 63, wv = tid >> 6;
    const int l15 = lane & 15, lhi = lane >> 4;
    const int srow = tid >> 2, sseg = tid & 3;

    // persistent qe fragments: rows = qg*256 + wv*64 + mt*16 + l15
    short8 af[4][4];
    #pragma unroll
    for (int mt = 0; mt < 4; ++mt)
        #pragma unroll
        for (int ks = 0; ks < 4; ++ks)
            af[mt][ks] = *(const short8*)(emb +
                (size_t)(qg*256 + wv*64 + mt*16 + l15) * E_DIM + ks*32 + lhi*8);

    float rmax[4][4];
    #pragma unroll
    for (int mt = 0; mt < 4; ++mt)
        #pragma unroll
        for (int r = 0; r < 4; ++r) rmax[mt][r] = -3.0e38f;

    const f32x4 zero4 = {0.f, 0.f, 0.f, 0.f};
    for (int ch = 0; ch < 3; ++ch) {
        int j = ch*64 + srow;
        int jv = (j < LD) ? j : 0;
        const unsigned short* src = emb + (size_t)(QTOK + d*LD + jv) * E_DIM + sseg*32;
        if (ch) __syncthreads();
        #pragma unroll
        for (int i = 0; i < 4; ++i) {
            short8 v = *(const short8*)(src + i*8);
            int byte = (srow * 256 + (sseg*32 + i*8) * 2) ^ ((srow & 7) << 4);
            *(short8*)(De + byte) = v;
        }
        __syncthreads();
        #pragma unroll
        for (int nt = 0; nt < 4; ++nt) {
            short8 bfr[4];
            int col = nt*16 + l15;
            #pragma unroll
            for (int ks = 0; ks < 4; ++ks) {
                int byte = (col * 256 + (ks*32 + lhi*8) * 2) ^ ((col & 7) << 4);
                bfr[ks] = *(const short8*)(De + byte);
            }
            f32x4 acc[4] = {zero4, zero4, zero4, zero4};
            #pragma unroll
            for (int ks = 0; ks < 4; ++ks)
                #pragma unroll
                for (int mt = 0; mt < 4; ++mt)
                    acc[mt] = __builtin_amdgcn_mfma_f32_16x16x32_bf16(
                        af[mt][ks], bfr[ks], acc[mt], 0, 0, 0);
            int jcol = ch*64 + nt*16 + l15;
            float mval = (jcol < LD) ? (float)dmask[d*LD + jcol] : -1.f;
            #pragma unroll
            for (int mt = 0; mt < 4; ++mt)
                #pragma unroll
                for (int r = 0; r < 4; ++r) {
                    float v = (mval < 0.f) ? -3.0e38f : acc[mt][r] * mval;
                    rmax[mt][r] = fmaxf(rmax[mt][r], v);
                }
        }
    }
    // max across the 16 col-lanes
    #pragma unroll
    for (int m1 = 1; m1 < 16; m1 <<= 1)
        #pragma unroll
        for (int mt = 0; mt < 4; ++mt)
            #pragma unroll
            for (int r = 0; r < 4; ++r)
                rmax[mt][r] = fmaxf(rmax[mt][r], __shfl_xor(rmax[mt][r], m1, 64));
    // per-q sums (wave holds 2 q's: rows mt<2 and mt>=2)
    float s0 = 0.f, s1 = 0.f;
    #pragma unroll
    for (int r = 0; r < 4; ++r) { s0 += rmax[0][r] + rmax[1][r]; s1 += rmax[2][r] + rmax[3][r]; }
    s0 += __shfl_xor(s0, 16, 64); s0 += __shfl_xor(s0, 32, 64);
    s1 += __shfl_xor(s1, 16, 64); s1 += __shfl_xor(s1, 32, 64);
    if (lane == 0) { red[wv*2 + 0] = s0; red[wv*2 + 1] = s1; }
    __syncthreads();
    if (tid < 8) {
        int q = qg*8 + tid;
        out[q * ND + d] = red[tid] / qcnt[q];
    }
}

extern "C" void kernel_launch(void* const* d_in, const int* in_sizes, int n_in,
                              void* d_out, int out_size, void* d_ws, size_t ws_size,
                              hipStream_t stream)
{
    const float* qh = (const float*)d_in[0];
    const float* dh = (const float*)d_in[1];
    const int*   qm = (const int*)d_in[2];
    const int*   dm = (const int*)d_in[3];
    const float* W1 = (const float*)d_in[4];
    const float* b1 = (const float*)d_in[5];
    const float* W2 = (const float*)d_in[6];
    const float* b2 = (const float*)d_in[7];
    float* out = (float*)d_out;

    unsigned short* emb = (unsigned short*)d_ws;                  // [48128][128] bf16
    unsigned short* W1T = emb + (size_t)TTOK * E_DIM;             // [768][768]
    unsigned short* W2T = W1T + (size_t)H_DIM * H_DIM;            // [128][768]
    float* qcnt = (float*)(W2T + (size_t)E_DIM * H_DIM);          // [64]
    size_t base_need = (size_t)TTOK*E_DIM*2 + (size_t)H_DIM*H_DIM*2
                     + (size_t)E_DIM*H_DIM*2 + 256;
    size_t xbf_need = (size_t)TTOK * H_DIM * 2;
    unsigned short* xbf = nullptr;
    if (ws_size >= base_need + xbf_need)
        xbf = (unsigned short*)((char*)d_ws + base_need);

    prep_kernel<<<256, 256, 0, stream>>>(W1, W2, qm, W1T, W2T, qcnt);
    head_kernel<<<TTOK / 64, 256, 0, stream>>>(qh, dh, qm, dm, b1, b2, W1T, W2T, emb, xbf);
    score_kernel<<<8 * ND, 256, 0, stream>>>(emb, dm, qcnt, out);
}

// Round 5
// 216.992 us; speedup vs baseline: 1.7899x; 1.1227x over previous
//
#include <hip/hip_runtime.h>
#include <hip/hip_bf16.h>

#define H_DIM 768
#define E_DIM 128
#define NQ 64
#define LQ 32
#define ND 256
#define LD 180
#define QTOK (NQ*LQ)          // 2048
#define DTOK (ND*LD)          // 46080
#define TTOK (QTOK+DTOK)      // 48128

typedef __attribute__((ext_vector_type(8))) short short8;
typedef __attribute__((ext_vector_type(4))) float f32x4;
typedef __attribute__((ext_vector_type(4))) float float4v;

__device__ __forceinline__ unsigned short f2bf(float f) {
    union { float f; unsigned u; } v;
    v.f = f;
    unsigned r = v.u + 0x7fffu + ((v.u >> 16) & 1u);
    return (unsigned short)(r >> 16);
}

__device__ __forceinline__ void gl_lds16(const void* g, void* l) {
    __builtin_amdgcn_global_load_lds(
        (const __attribute__((address_space(1))) unsigned char*)g,
        (__attribute__((address_space(3))) unsigned char*)l, 16, 0, 0);
}

// ---------------------------------------------------------------------------
// prep: W1T/W2T bf16 transposes (write-coalesced), qcnt, and X -> xbf2 in
// MFMA fragment layout [16-row group][kb][ks][lhi][l15][8]. Every output
// element written by exactly one thread — no cross-thread hazards.
// ---------------------------------------------------------------------------
__global__ __launch_bounds__(256) void prep_kernel(
    const float* __restrict__ qh, const float* __restrict__ dh,
    const float* __restrict__ W1, const float* __restrict__ W2,
    const int* __restrict__ qmask,
    unsigned short* __restrict__ W1T, unsigned short* __restrict__ W2T,
    float* __restrict__ qcnt, unsigned short* __restrict__ xbf2)
{
    int tid = blockIdx.x * 256 + threadIdx.x;
    int nth = gridDim.x * 256;
    for (int o = tid; o < H_DIM * H_DIM; o += nth) {
        int c = o / H_DIM, k = o - c * H_DIM;
        W1T[o] = f2bf(W1[(size_t)k * H_DIM + c]);
    }
    for (int o = tid; o < E_DIM * H_DIM; o += nth) {
        int c = o / H_DIM, k = o - c * H_DIM;
        W2T[o] = f2bf(W2[(size_t)k * E_DIM + c]);
    }
    if (tid < NQ) {
        int s = 0;
        for (int i = 0; i < LQ; ++i) s += qmask[tid * LQ + i];
        qcnt[tid] = (float)s;
    }
    if (xbf2) {
        const int NSLOT = (TTOK / 16) * 12 * 128;
        for (int S = tid; S < NSLOT; S += nth) {
            int sic = S & 127;
            int chunk = S >> 7;
            int kb = chunk % 12;
            int g  = chunk / 12;
            int ks  = sic >> 6;
            int lh2 = (sic >> 4) & 3;
            int L   = sic & 15;
            int row = g * 16 + L;
            int k0  = kb * 64 + ks * 32 + lh2 * 8;
            const float* src = (row < QTOK)
                ? (qh + (size_t)row * H_DIM + k0)
                : (dh + (size_t)(row - QTOK) * H_DIM + k0);
            float4v a = ((const float4v*)src)[0];
            float4v b = ((const float4v*)src)[1];
            union { unsigned short u[8]; short8 s8; } t;
            t.u[0] = f2bf(a.x); t.u[1] = f2bf(a.y); t.u[2] = f2bf(a.z); t.u[3] = f2bf(a.w);
            t.u[4] = f2bf(b.x); t.u[5] = f2bf(b.y); t.u[6] = f2bf(b.z); t.u[7] = f2bf(b.w);
            *(short8*)(xbf2 + (size_t)S * 8) = t.s8;
        }
    }
}

// ---------------------------------------------------------------------------
// head: BM=64, 4 waves (2Mx2N). PROVEN m97-style schedule — single Bbuf,
// two barriers per step: sync (readers done) -> STAGE -> afx load (overlap)
// -> sync (stage drained) -> ds_read + MFMA. No load crosses a barrier.
// LDS 32KB: Bbuf 16K | T1 16K -> 4-5 blocks/CU for cross-block latency hiding.
// A-fragments: one coalesced 1KB/wave transaction from fragment-layout xbf2.
// ---------------------------------------------------------------------------
__global__ __launch_bounds__(256, 4) void head_kernel(
    const float* __restrict__ qh, const float* __restrict__ dh,
    const int* __restrict__ qmv, const int* __restrict__ dmv,
    const float* __restrict__ b1, const float* __restrict__ b2,
    const unsigned short* __restrict__ W1T, const unsigned short* __restrict__ W2T,
    unsigned short* __restrict__ emb, const unsigned short* __restrict__ xbf2)
{
    __shared__ char lds[32768];
    char* Bbuf = lds;            // 16K [128 cols][64 k] bf16, swz
    char* T1   = lds + 16384;    // 16K [64 rows][128 cols] bf16, swz

    const int tid = threadIdx.x, lane = tid & 63, wv = tid >> 6;
    const int wm = wv >> 1, wn = wv & 1;
    const int l15 = lane & 15, lhi = lane >> 4;
    const int t0 = blockIdx.x * 64;
    const float* xsrc = (t0 < QTOK) ? (qh + (size_t)t0 * H_DIM)
                                    : (dh + (size_t)(t0 - QTOK) * H_DIM);

    // pre-swizzled source coords for Bbuf staging (linear LDS dest, rule 21)
    int bcol[4], bk[4];
    #pragma unroll
    for (int i = 0; i < 4; ++i) {
        int o = i * 4096 + wv * 1024 + lane * 16;
        int col = o >> 7;
        bcol[i] = col;
        bk[i] = ((o & 127) ^ ((col & 7) << 4)) >> 1;
    }

    #define STAGE_W1(JB, KB) do {                                              \
        _Pragma("unroll")                                                      \
        for (int i_ = 0; i_ < 4; ++i_)                                         \
            gl_lds16(W1T + (size_t)((JB)*128 + bcol[i_]) * H_DIM + (KB)*64 + bk[i_], \
                     Bbuf + i_*4096 + wv*1024);                                \
    } while (0)
    #define STAGE_W2(JB, HH) do {                                              \
        _Pragma("unroll")                                                      \
        for (int i_ = 0; i_ < 4; ++i_)                                         \
            gl_lds16(W2T + (size_t)bcol[i_] * H_DIM + (JB)*128 + (HH)*64 + bk[i_], \
                     Bbuf + i_*4096 + wv*1024);                                \
    } while (0)

    const f32x4 zero4 = {0.f, 0.f, 0.f, 0.f};
    f32x4 eacc[2][4];
    #pragma unroll
    for (int mt = 0; mt < 2; ++mt)
        #pragma unroll
        for (int nt = 0; nt < 4; ++nt) eacc[mt][nt] = zero4;

    #pragma unroll 1
    for (int jb = 0; jb < 6; ++jb) {
        f32x4 pacc[2][4];
        #pragma unroll
        for (int mt = 0; mt < 2; ++mt)
            #pragma unroll
            for (int nt = 0; nt < 4; ++nt) pacc[mt][nt] = zero4;

        #pragma unroll 1
        for (int kb = 0; kb < 12; ++kb) {
            __syncthreads();              // previous step's Bbuf reads done
            STAGE_W1(jb, kb);

            short8 afx[2][2];
            if (xbf2) {
                #pragma unroll
                for (int mt = 0; mt < 2; ++mt)
                    #pragma unroll
                    for (int ks = 0; ks < 2; ++ks) {
                        size_t r16 = (size_t)(t0 >> 4) + wm * 2 + mt;
                        afx[mt][ks] = *(const short8*)(xbf2 +
                            ((r16 * 12 + kb) * 2 + ks) * 512 + lhi * 128 + l15 * 8);
                    }
            } else {
                #pragma unroll
                for (int mt = 0; mt < 2; ++mt)
                    #pragma unroll
                    for (int ks = 0; ks < 2; ++ks) {
                        const float* p = xsrc + (size_t)(wm*32 + mt*16 + l15) * H_DIM + kb*64 + ks*32 + lhi*8;
                        float4v a = ((const float4v*)p)[0], b = ((const float4v*)p)[1];
                        union { unsigned short u[8]; short8 s8; } tt;
                        tt.u[0]=f2bf(a.x); tt.u[1]=f2bf(a.y); tt.u[2]=f2bf(a.z); tt.u[3]=f2bf(a.w);
                        tt.u[4]=f2bf(b.x); tt.u[5]=f2bf(b.y); tt.u[6]=f2bf(b.z); tt.u[7]=f2bf(b.w);
                        afx[mt][ks] = tt.s8;
                    }
            }
            __syncthreads();              // stage drained (vmcnt0 before barrier)

            #pragma unroll
            for (int ks = 0; ks < 2; ++ks) {
                short8 bfr[4];
                #pragma unroll
                for (int nt = 0; nt < 4; ++nt) {
                    int col = wn * 64 + nt * 16 + l15;
                    int byte = (col * 128 + (ks * 32 + lhi * 8) * 2) ^ ((col & 7) << 4);
                    bfr[nt] = *(const short8*)(Bbuf + byte);
                }
                // swapped operands: pacc = T1^T fragment (lane holds 4 consecutive cols)
                #pragma unroll
                for (int nt = 0; nt < 4; ++nt)
                    #pragma unroll
                    for (int mt = 0; mt < 2; ++mt)
                        pacc[mt][nt] = __builtin_amdgcn_mfma_f32_16x16x32_bf16(
                            bfr[nt], afx[mt][ks], pacc[mt][nt], 0, 0, 0);
            }
        }

        // T1 write: bias+relu, 4 consecutive cols per b64 write (own cells;
        // made visible to other waves by the h=0 first barrier)
        #pragma unroll
        for (int mt = 0; mt < 2; ++mt) {
            int token = wm * 32 + mt * 16 + l15;
            int sw = (token & 7) << 4;
            #pragma unroll
            for (int nt = 0; nt < 4; ++nt) {
                int c0 = wn * 64 + nt * 16 + lhi * 4;
                union { unsigned short u[4]; unsigned long long q; } pk;
                #pragma unroll
                for (int r = 0; r < 4; ++r) {
                    float v = pacc[mt][nt][r] + b1[jb * 128 + c0 + r];
                    v = v > 0.f ? v : 0.f;
                    pk.u[r] = f2bf(v);
                }
                int byte = (token * 256 + c0 * 2) ^ sw;
                *(unsigned long long*)(T1 + byte) = pk.q;
            }
        }

        // phase B: eacc += T1 @ W2[jb-panel], two 64-k halves through Bbuf
        #pragma unroll 1
        for (int h = 0; h < 2; ++h) {
            __syncthreads();              // T1 visible; Bbuf readers done
            STAGE_W2(jb, h);
            __syncthreads();              // stage drained
            #pragma unroll
            for (int ks = 0; ks < 2; ++ks) {
                short8 at[2], bw[4];
                #pragma unroll
                for (int mt = 0; mt < 2; ++mt) {
                    int row = wm * 32 + mt * 16 + l15;
                    int byte = (row * 256 + (h * 64 + ks * 32 + lhi * 8) * 2) ^ ((row & 7) << 4);
                    at[mt] = *(const short8*)(T1 + byte);
                }
                #pragma unroll
                for (int nt = 0; nt < 4; ++nt) {
                    int col = wn * 64 + nt * 16 + l15;
                    int byte = (col * 128 + (ks * 32 + lhi * 8) * 2) ^ ((col & 7) << 4);
                    bw[nt] = *(const short8*)(Bbuf + byte);
                }
                #pragma unroll
                for (int mt = 0; mt < 2; ++mt)
                    #pragma unroll
                    for (int nt = 0; nt < 4; ++nt)
                        eacc[mt][nt] = __builtin_amdgcn_mfma_f32_16x16x32_bf16(
                            at[mt], bw[nt], eacc[mt][nt], 0, 0, 0);
            }
        }
    }

    // epilogue: +b2, mask, L2-normalize, store bf16
    float* rs = (float*)lds;   // aliases Bbuf (guarded by barriers below)
    float b2v[4];
    #pragma unroll
    for (int nt = 0; nt < 4; ++nt) b2v[nt] = b2[wn*64 + nt*16 + l15];

    float vals[2][4][4], sq[2][4];
    #pragma unroll
    for (int mt = 0; mt < 2; ++mt)
        #pragma unroll
        for (int r = 0; r < 4; ++r) {
            int ri = mt*16 + lhi*4 + r;
            int t = t0 + wm*32 + ri;
            float fm = (float)((t < QTOK) ? qmv[t] : dmv[t - QTOK]);
            float s = 0.f;
            #pragma unroll
            for (int nt = 0; nt < 4; ++nt) {
                float v = (eacc[mt][nt][r] + b2v[nt]) * fm;
                vals[mt][nt][r] = v;
                s += v * v;
            }
            sq[mt][r] = s;
        }
    #pragma unroll
    for (int m1 = 1; m1 < 16; m1 <<= 1)
        #pragma unroll
        for (int mt = 0; mt < 2; ++mt)
            #pragma unroll
            for (int r = 0; r < 4; ++r)
                sq[mt][r] += __shfl_xor(sq[mt][r], m1, 64);
    __syncthreads();
    if (l15 == 0) {
        #pragma unroll
        for (int mt = 0; mt < 2; ++mt)
            #pragma unroll
            for (int r = 0; r < 4; ++r)
                rs[wv*32 + mt*16 + lhi*4 + r] = sq[mt][r];
    }
    __syncthreads();
    #pragma unroll
    for (int mt = 0; mt < 2; ++mt)
        #pragma unroll
        for (int r = 0; r < 4; ++r) {
            int ri = mt*16 + lhi*4 + r;
            float tot = rs[(wm*2)*32 + ri] + rs[(wm*2+1)*32 + ri];
            float sc = 1.f / fmaxf(sqrtf(tot), 1e-12f);
            int t = t0 + wm*32 + ri;
            #pragma unroll
            for (int nt = 0; nt < 4; ++nt)
                emb[(size_t)t * E_DIM + wn*64 + nt*16 + l15] = f2bf(vals[mt][nt][r] * sc);
        }
    #undef STAGE_W1
    #undef STAGE_W2
}

// ---------------------------------------------------------------------------
// score: block = (8-q group, d); qe persistent in regs; de staged in LDS.
// (unchanged — proven in rounds 2)
// ---------------------------------------------------------------------------
__global__ __launch_bounds__(256, 3) void score_kernel(
    const unsigned short* __restrict__ emb, const int* __restrict__ dmask,
    const float* __restrict__ qcnt, float* __restrict__ out)
{
    __shared__ char slds[16384 + 64];
    char* De = slds;
    float* red = (float*)(slds + 16384);

    const int d = blockIdx.x & 255;
    const int qg = blockIdx.x >> 8;
    const int tid = threadIdx.x, lane = tid & 63, wv = tid >> 6;
    const int l15 = lane & 15, lhi = lane >> 4;
    const int srow = tid >> 2, sseg = tid & 3;

    short8 af[4][4];
    #pragma unroll
    for (int mt = 0; mt < 4; ++mt)
        #pragma unroll
        for (int ks = 0; ks < 4; ++ks)
            af[mt][ks] = *(const short8*)(emb +
                (size_t)(qg*256 + wv*64 + mt*16 + l15) * E_DIM + ks*32 + lhi*8);

    float rmax[4][4];
    #pragma unroll
    for (int mt = 0; mt < 4; ++mt)
        #pragma unroll
        for (int r = 0; r < 4; ++r) rmax[mt][r] = -3.0e38f;

    const f32x4 zero4 = {0.f, 0.f, 0.f, 0.f};
    for (int ch = 0; ch < 3; ++ch) {
        int j = ch*64 + srow;
        int jv = (j < LD) ? j : 0;
        const unsigned short* src = emb + (size_t)(QTOK + d*LD + jv) * E_DIM + sseg*32;
        if (ch) __syncthreads();
        #pragma unroll
        for (int i = 0; i < 4; ++i) {
            short8 v = *(const short8*)(src + i*8);
            int byte = (srow * 256 + (sseg*32 + i*8) * 2) ^ ((srow & 7) << 4);
            *(short8*)(De + byte) = v;
        }
        __syncthreads();
        #pragma unroll
        for (int nt = 0; nt < 4; ++nt) {
            short8 bfr[4];
            int col = nt*16 + l15;
            #pragma unroll
            for (int ks = 0; ks < 4; ++ks) {
                int byte = (col * 256 + (ks*32 + lhi*8) * 2) ^ ((col & 7) << 4);
                bfr[ks] = *(const short8*)(De + byte);
            }
            f32x4 acc[4] = {zero4, zero4, zero4, zero4};
            #pragma unroll
            for (int ks = 0; ks < 4; ++ks)
                #pragma unroll
                for (int mt = 0; mt < 4; ++mt)
                    acc[mt] = __builtin_amdgcn_mfma_f32_16x16x32_bf16(
                        af[mt][ks], bfr[ks], acc[mt], 0, 0, 0);
            int jcol = ch*64 + nt*16 + l15;
            float mval = (jcol < LD) ? (float)dmask[d*LD + jcol] : -1.f;
            #pragma unroll
            for (int mt = 0; mt < 4; ++mt)
                #pragma unroll
                for (int r = 0; r < 4; ++r) {
                    float v = (mval < 0.f) ? -3.0e38f : acc[mt][r] * mval;
                    rmax[mt][r] = fmaxf(rmax[mt][r], v);
                }
        }
    }
    #pragma unroll
    for (int m1 = 1; m1 < 16; m1 <<= 1)
        #pragma unroll
        for (int mt = 0; mt < 4; ++mt)
            #pragma unroll
            for (int r = 0; r < 4; ++r)
                rmax[mt][r] = fmaxf(rmax[mt][r], __shfl_xor(rmax[mt][r], m1, 64));
    float s0 = 0.f, s1 = 0.f;
    #pragma unroll
    for (int r = 0; r < 4; ++r) { s0 += rmax[0][r] + rmax[1][r]; s1 += rmax[2][r] + rmax[3][r]; }
    s0 += __shfl_xor(s0, 16, 64); s0 += __shfl_xor(s0, 32, 64);
    s1 += __shfl_xor(s1, 16, 64); s1 += __shfl_xor(s1, 32, 64);
    if (lane == 0) { red[wv*2 + 0] = s0; red[wv*2 + 1] = s1; }
    __syncthreads();
    if (tid < 8) {
        int q = qg*8 + tid;
        out[q * ND + d] = red[tid] / qcnt[q];
    }
}

extern "C" void kernel_launch(void* const* d_in, const int* in_sizes, int n_in,
                              void* d_out, int out_size, void* d_ws, size_t ws_size,
                              hipStream_t stream)
{
    const float* qh = (const float*)d_in[0];
    const float* dh = (const float*)d_in[1];
    const int*   qm = (const int*)d_in[2];
    const int*   dm = (const int*)d_in[3];
    const float* W1 = (const float*)d_in[4];
    const float* b1 = (const float*)d_in[5];
    const float* W2 = (const float*)d_in[6];
    const float* b2 = (const float*)d_in[7];
    float* out = (float*)d_out;

    unsigned short* emb = (unsigned short*)d_ws;                  // [48128][128] bf16
    unsigned short* W1T = emb + (size_t)TTOK * E_DIM;             // [768][768]
    unsigned short* W2T = W1T + (size_t)H_DIM * H_DIM;            // [128][768]
    float* qcnt = (float*)(W2T + (size_t)E_DIM * H_DIM);          // [64]
    size_t base_need = (size_t)TTOK*E_DIM*2 + (size_t)H_DIM*H_DIM*2
                     + (size_t)E_DIM*H_DIM*2 + 256;
    size_t xbf_need = (size_t)TTOK * H_DIM * 2;
    unsigned short* xbf2 = nullptr;
    if (ws_size >= base_need + xbf_need)
        xbf2 = (unsigned short*)((char*)d_ws + base_need);

    prep_kernel<<<2048, 256, 0, stream>>>(qh, dh, W1, W2, qm, W1T, W2T, qcnt, xbf2);
    head_kernel<<<TTOK / 64, 256, 0, stream>>>(qh, dh, qm, dm, b1, b2, W1T, W2T, emb, xbf2);
    score_kernel<<<8 * ND, 256, 0, stream>>>(emb, dm, qcnt, out);
}